// Round 2
// baseline (529.713 us; speedup 1.0000x reference)
//
#include <hip/hip_runtime.h>

namespace {

constexpr int B = 64;
constexpr int N = 64;
constexpr int D = 64;
constexpr int E = 2 * D + 1;  // 129

// One block per (i,j) pair; early-exit if not an edge.
// Computes msg[b,i,j,:] for all b and atomically accumulates into agg[b,i,:].
__global__ __launch_bounds__(256) void k_msg(
    const float* __restrict__ sin,   // [B][N][D] (x for layer 0, s otherwise)
    const float* __restrict__ ew,    // [N][N]
    const float* __restrict__ Wm,    // [N][N][E][D]  (layer slice)
    const float* __restrict__ bm,    // [N][N][D]     (layer slice)
    float* __restrict__ agg)         // [B][N][D]
{
  const int ij = blockIdx.x;
  const float w = ew[ij];
  if (w == 0.0f) return;  // uniform across block
  const int i = ij >> 6;
  const int j = ij & 63;

  __shared__ float siT[D][B];  // siT[k][b] = sin[b][i][k]
  __shared__ float sjT[D][B];

  const int t = threadIdx.x;
  {
    const int bb = t >> 2;   // 0..63
    const int q  = t & 3;    // 0..3
    const float* ps = sin + ((size_t)bb * N + i) * D;
    const float* pq = sin + ((size_t)bb * N + j) * D;
#pragma unroll
    for (int kc = 0; kc < 4; ++kc) {
      const int k0 = kc * 16 + q * 4;
      float4 v = *(const float4*)(ps + k0);
      siT[k0 + 0][bb] = v.x;
      siT[k0 + 1][bb] = v.y;
      siT[k0 + 2][bb] = v.z;
      siT[k0 + 3][bb] = v.w;
      float4 u2 = *(const float4*)(pq + k0);
      sjT[k0 + 0][bb] = u2.x;
      sjT[k0 + 1][bb] = u2.y;
      sjT[k0 + 2][bb] = u2.z;
      sjT[k0 + 3][bb] = u2.w;
    }
  }
  __syncthreads();

  const int b  = t & 63;                                       // lane = batch
  const int d0 = __builtin_amdgcn_readfirstlane(t >> 6) * 16;  // wave-uniform d-chunk
  const float* __restrict__ Wp = Wm + (size_t)ij * (E * D);

  float acc[16];
#pragma unroll
  for (int u = 0; u < 16; ++u)
    acc[u] = w * Wp[(size_t)(2 * D) * D + d0 + u] + bm[(size_t)ij * D + d0 + u];

#pragma unroll 2
  for (int k = 0; k < D; ++k) {
    const float a  = siT[k][b];
    const float c2 = sjT[k][b];
    const float* __restrict__ w1 = Wp + (size_t)k * D + d0;        // feat_i part
    const float* __restrict__ w2 = Wp + (size_t)(D + k) * D + d0;  // feat_j part
#pragma unroll
    for (int u = 0; u < 16; ++u)
      acc[u] += a * w1[u] + c2 * w2[u];
  }

  float* ap = agg + ((size_t)b * N + i) * D + d0;
#pragma unroll
  for (int u = 0; u < 16; ++u)
    atomicAdd(ap + u, acc[u]);
}

// One block per batch b: update MLP + residual mix, sequential node scan in
// LDS; zeroes agg for the next layer. LAST variant fuses the readout + output
// projection and skips the s writeback.
template <bool LAST>
__global__ __launch_bounds__(256) void k_upd(
    const float* __restrict__ sin,  // [B][N][D] (x for layer 0, s otherwise)
    float* __restrict__ s,          // [B][N][D] out (non-LAST)
    float* __restrict__ agg,        // [B][N][D]; zeroed here (non-LAST)
    const float* __restrict__ ew,   // [N][N]
    const float* __restrict__ Wu,   // [2D][D] (layer slice)
    const float* __restrict__ bu,   // [D]     (layer slice)
    const float* __restrict__ Wo,   // [D][D]
    const float* __restrict__ bo,   // [D]
    float* __restrict__ out)        // [B][D]
{
  const int b = blockIdx.x;
  const int t = threadIdx.x;

  __shared__ float catT[2 * D][N];   // catT[k][i]: k<D -> sin, k>=D -> agg
  __shared__ float sb[N][D + 1];     // padded scan state
  __shared__ float degf[N];
  __shared__ int   cnt[N];
  __shared__ unsigned char nbr[N][64];

  {
    const int ii = t >> 2;
    const int q  = t & 3;
    const float* ps = sin + ((size_t)b * N + ii) * D;
    float*       pa = agg + ((size_t)b * N + ii) * D;
#pragma unroll
    for (int kc = 0; kc < 4; ++kc) {
      const int k0 = kc * 16 + q * 4;
      float4 v = *(const float4*)(ps + k0);
      catT[k0 + 0][ii] = v.x;
      catT[k0 + 1][ii] = v.y;
      catT[k0 + 2][ii] = v.z;
      catT[k0 + 3][ii] = v.w;
      float4 u2 = *(const float4*)(pa + k0);
      catT[D + k0 + 0][ii] = u2.x;
      catT[D + k0 + 1][ii] = u2.y;
      catT[D + k0 + 2][ii] = u2.z;
      catT[D + k0 + 3][ii] = u2.w;
      if (!LAST) *(float4*)(pa + k0) = make_float4(0.f, 0.f, 0.f, 0.f);
    }
  }
  if (t < N) {
    int c = 0;
    for (int jj = 0; jj < N; ++jj)
      if (ew[t * N + jj] > 0.0f) nbr[t][c++] = (unsigned char)jj;
    cnt[t]  = c;
    degf[t] = (float)c;
  }
  __syncthreads();

  // upd GEMM: lane = i, wave-uniform d-chunk
  const int i  = t & 63;
  const int d0 = __builtin_amdgcn_readfirstlane(t >> 6) * 16;

  float acc[16];
#pragma unroll
  for (int u = 0; u < 16; ++u) acc[u] = bu[d0 + u];

#pragma unroll 2
  for (int k = 0; k < 2 * D; ++k) {
    const float a = catT[k][i];
    const float* __restrict__ wr = Wu + (size_t)k * D + d0;
#pragma unroll
    for (int u = 0; u < 16; ++u) acc[u] += a * wr[u];
  }
#pragma unroll
  for (int u = 0; u < 16; ++u)
    sb[i][d0 + u] = 0.9f * acc[u] + 0.1f * catT[d0 + u][i];
  __syncthreads();

  // sequential scan over nodes; lane d owns column d of sb (wave 0 only)
  if (t < N) {
    const int d = t;
    for (int ii = 0; ii < N; ++ii) {
      const int c = cnt[ii];
      float nb = 0.0f;
      for (int q2 = 0; q2 < c; ++q2) nb += sb[nbr[ii][q2]][d];
      const float dg  = degf[ii];
      const float avg = nb / fmaxf(dg, 1.0f);
      const float cur = sb[ii][d];
      sb[ii][d] = (dg > 0.0f) ? (0.95f * cur + 0.05f * avg) : cur;
    }
    if (LAST) {
      // readout: c-weights, g, final projection — all within wave 0
      float ci = 0.0f;
      for (int jj = 0; jj < N; ++jj) ci += ew[d * N + jj];
      float tot = ci;
#pragma unroll
      for (int off = 32; off >= 1; off >>= 1) tot += __shfl_xor(tot, off, 64);
      const float cv = ci / (tot + 1e-8f);

      float g = 0.0f;
      for (int i2 = 0; i2 < N; ++i2) g += __shfl(cv, i2, 64) * sb[i2][d];

      float o = bo[d];
      for (int k2 = 0; k2 < D; ++k2) o += __shfl(g, k2, 64) * Wo[k2 * D + d];
      out[(size_t)b * D + d] = o;
    }
  }

  if (!LAST) {
    __syncthreads();
    const int ii = t >> 2;
    const int q  = t & 3;
    float* ps = s + ((size_t)b * N + ii) * D;
#pragma unroll
    for (int kc = 0; kc < 4; ++kc) {
      const int k0 = kc * 16 + q * 4;
      float4 v;
      v.x = sb[ii][k0 + 0];
      v.y = sb[ii][k0 + 1];
      v.z = sb[ii][k0 + 2];
      v.w = sb[ii][k0 + 3];
      *(float4*)(ps + k0) = v;
    }
  }
}

}  // namespace

extern "C" void kernel_launch(void* const* d_in, const int* in_sizes, int n_in,
                              void* d_out, int out_size, void* d_ws, size_t ws_size,
                              hipStream_t stream)
{
  const float* x  = (const float*)d_in[0];
  const float* ew = (const float*)d_in[1];
  const float* Wm = (const float*)d_in[2];
  const float* bm = (const float*)d_in[3];
  const float* Wu = (const float*)d_in[4];
  const float* bu = (const float*)d_in[5];
  const float* Wo = (const float*)d_in[6];
  const float* bo = (const float*)d_in[7];
  float* out = (float*)d_out;

  float* s   = (float*)d_ws;
  float* agg = s + (size_t)B * N * D;

  const int L = in_sizes[2] / (N * N * E * D);  // = 3

  hipMemsetAsync(agg, 0, (size_t)B * N * D * sizeof(float), stream);

  for (int l = 0; l < L; ++l) {
    const float* sin_p = (l == 0) ? x : s;
    k_msg<<<N * N, 256, 0, stream>>>(
        sin_p, ew,
        Wm + (size_t)l * N * N * E * D,
        bm + (size_t)l * N * N * D,
        agg);
    if (l < L - 1) {
      k_upd<false><<<B, 256, 0, stream>>>(
          sin_p, s, agg, ew,
          Wu + (size_t)l * 2 * D * D, bu + (size_t)l * D,
          Wo, bo, out);
    } else {
      k_upd<true><<<B, 256, 0, stream>>>(
          sin_p, s, agg, ew,
          Wu + (size_t)l * 2 * D * D, bu + (size_t)l * D,
          Wo, bo, out);
    }
  }
}

// Round 3
// 459.069 us; speedup vs baseline: 1.1539x; 1.1539x over previous
//
#include <hip/hip_runtime.h>

namespace {

constexpr int B = 64;
constexpr int N = 64;
constexpr int D = 64;
constexpr int E = 2 * D + 1;  // 129

// Grid (N*N, 2); block 256. One block per (i,j,d-half); early-exit on non-edge.
// Accumulates msg[b,i,j,d-half] into agg[b,i,:] via atomics.
__global__ __launch_bounds__(256) void k_msg(
    const float* __restrict__ sin,   // [B][N][D] (x for layer 0, s otherwise)
    const float* __restrict__ ew,    // [N][N]
    const float* __restrict__ Wm,    // [N][N][E][D]  (layer slice)
    const float* __restrict__ bm,    // [N][N][D]     (layer slice)
    float* __restrict__ agg)         // [B][N][D]
{
  const int ij = blockIdx.x;
  const float w = ew[ij];
  if (w == 0.0f) return;  // uniform across block
  const int i = ij >> 6;
  const int j = ij & 63;

  __shared__ float siT[D][B];  // siT[k][b] = sin[b][i][k]
  __shared__ float sjT[D][B];

  const int t = threadIdx.x;
  {
    const int bb = t >> 2;   // 0..63
    const int q  = t & 3;    // 0..3
    const float* ps = sin + ((size_t)bb * N + i) * D;
    const float* pq = sin + ((size_t)bb * N + j) * D;
#pragma unroll
    for (int kc = 0; kc < 4; ++kc) {
      const int k0 = kc * 16 + q * 4;
      float4 v = *(const float4*)(ps + k0);
      siT[k0 + 0][bb] = v.x;
      siT[k0 + 1][bb] = v.y;
      siT[k0 + 2][bb] = v.z;
      siT[k0 + 3][bb] = v.w;
      float4 u2 = *(const float4*)(pq + k0);
      sjT[k0 + 0][bb] = u2.x;
      sjT[k0 + 1][bb] = u2.y;
      sjT[k0 + 2][bb] = u2.z;
      sjT[k0 + 3][bb] = u2.w;
    }
  }
  __syncthreads();

  const int b  = t & 63;  // lane = batch
  const int d0 = blockIdx.y * 32 + __builtin_amdgcn_readfirstlane(t >> 6) * 8;
  const float* __restrict__ Wp = Wm + (size_t)ij * (E * D);

  float acc[8];
#pragma unroll
  for (int u = 0; u < 8; ++u)
    acc[u] = w * Wp[(size_t)(2 * D) * D + d0 + u] + bm[(size_t)ij * D + d0 + u];

#pragma unroll 4
  for (int k = 0; k < D; ++k) {
    const float a  = siT[k][b];
    const float c2 = sjT[k][b];
    const float* __restrict__ w1 = Wp + (size_t)k * D + d0;        // feat_i part
    const float* __restrict__ w2 = Wp + (size_t)(D + k) * D + d0;  // feat_j part
#pragma unroll
    for (int u = 0; u < 8; ++u)
      acc[u] += a * w1[u] + c2 * w2[u];
  }

  float* ap = agg + ((size_t)b * N + i) * D + d0;
#pragma unroll
  for (int u = 0; u < 8; ++u)
    atomicAdd(ap + u, acc[u]);
}

// One block per batch b: update MLP + residual mix, sequential node scan in
// LDS; zeroes agg for the next layer. LAST variant fuses the readout + output
// projection and skips the s writeback.
template <bool LAST>
__global__ __launch_bounds__(256) void k_upd(
    const float* __restrict__ sin,  // [B][N][D] (x for layer 0, s otherwise)
    float* __restrict__ s,          // [B][N][D] out (non-LAST)
    float* __restrict__ agg,        // [B][N][D]; zeroed here (non-LAST)
    const float* __restrict__ ew,   // [N][N]
    const float* __restrict__ Wu,   // [2D][D] (layer slice)
    const float* __restrict__ bu,   // [D]     (layer slice)
    const float* __restrict__ Wo,   // [D][D]
    const float* __restrict__ bo,   // [D]
    float* __restrict__ out)        // [B][D]
{
  const int b = blockIdx.x;
  const int t = threadIdx.x;

  __shared__ float catT[2 * D][N];   // catT[k][i]: k<D -> sin, k>=D -> agg
  __shared__ float sb[N][D + 1];     // padded scan state
  __shared__ float degf[N];
  __shared__ int   cnt[N];
  __shared__ unsigned char nbr[N][64];  // row = node, 16B-aligned rows

  {
    const int ii = t >> 2;
    const int q  = t & 3;
    const float* ps = sin + ((size_t)b * N + ii) * D;
    float*       pa = agg + ((size_t)b * N + ii) * D;
#pragma unroll
    for (int kc = 0; kc < 4; ++kc) {
      const int k0 = kc * 16 + q * 4;
      float4 v = *(const float4*)(ps + k0);
      catT[k0 + 0][ii] = v.x;
      catT[k0 + 1][ii] = v.y;
      catT[k0 + 2][ii] = v.z;
      catT[k0 + 3][ii] = v.w;
      float4 u2 = *(const float4*)(pa + k0);
      catT[D + k0 + 0][ii] = u2.x;
      catT[D + k0 + 1][ii] = u2.y;
      catT[D + k0 + 2][ii] = u2.z;
      catT[D + k0 + 3][ii] = u2.w;
      if (!LAST) *(float4*)(pa + k0) = make_float4(0.f, 0.f, 0.f, 0.f);
    }
  }
  if (t < N) {
    int c = 0;
    for (int jj = 0; jj < N; ++jj)
      if (ew[t * N + jj] > 0.0f) nbr[t][c++] = (unsigned char)jj;
    cnt[t]  = c;
    degf[t] = (float)c;
  }
  __syncthreads();

  // upd GEMM: lane = i, wave-uniform d-chunk
  const int i  = t & 63;
  const int d0 = __builtin_amdgcn_readfirstlane(t >> 6) * 16;

  float acc[16];
#pragma unroll
  for (int u = 0; u < 16; ++u) acc[u] = bu[d0 + u];

#pragma unroll 4
  for (int k = 0; k < 2 * D; ++k) {
    const float a = catT[k][i];
    const float* __restrict__ wr = Wu + (size_t)k * D + d0;
#pragma unroll
    for (int u = 0; u < 16; ++u) acc[u] += a * wr[u];
  }
#pragma unroll
  for (int u = 0; u < 16; ++u)
    sb[i][d0 + u] = 0.9f * acc[u] + 0.1f * catT[d0 + u][i];
  __syncthreads();

  // sequential scan over nodes; lane d owns column d of sb (wave 0 only).
  // Neighbor ids packed: one ds_read_b128 gives 16 slots -> independent
  // predicated sb reads (no dependent nbr->sb chain); prefetch next node.
  if (t < N) {
    const int d = t;
    uint4 w = *(const uint4*)&nbr[0][0];
    int   c = cnt[0];
    float dg = degf[0];
    for (int ii = 0; ii < N; ++ii) {
      uint4 wn = w; int cn = c; float dgn = dg;
      if (ii < N - 1) {
        wn  = *(const uint4*)&nbr[ii + 1][0];
        cn  = cnt[ii + 1];
        dgn = degf[ii + 1];
      }
      const unsigned wd[4] = {w.x, w.y, w.z, w.w};
      float nb = 0.0f;
#pragma unroll
      for (int q = 0; q < 8; ++q) {
        const int idx = (int)((wd[q >> 2] >> ((q & 3) * 8)) & 63u);
        const float v = sb[idx][d];
        nb += (q < c) ? v : 0.0f;
      }
      if (c > 8) {
#pragma unroll
        for (int q = 8; q < 16; ++q) {
          const int idx = (int)((wd[q >> 2] >> ((q & 3) * 8)) & 63u);
          const float v = sb[idx][d];
          nb += (q < c) ? v : 0.0f;
        }
        for (int q = 16; q < c; ++q) nb += sb[nbr[ii][q]][d];  // rare tail
      }
      const float avg = nb / fmaxf(dg, 1.0f);
      const float cur = sb[ii][d];
      sb[ii][d] = (dg > 0.0f) ? (0.95f * cur + 0.05f * avg) : cur;
      w = wn; c = cn; dg = dgn;
    }
    if (LAST) {
      // readout: c-weights, g, final projection — all within wave 0
      float ci = 0.0f;
      for (int jj = 0; jj < N; ++jj) ci += ew[d * N + jj];
      float tot = ci;
#pragma unroll
      for (int off = 32; off >= 1; off >>= 1) tot += __shfl_xor(tot, off, 64);
      const float cv = ci / (tot + 1e-8f);

      float g = 0.0f;
      for (int i2 = 0; i2 < N; ++i2) g += __shfl(cv, i2, 64) * sb[i2][d];

      float o = bo[d];
      for (int k2 = 0; k2 < D; ++k2) o += __shfl(g, k2, 64) * Wo[k2 * D + d];
      out[(size_t)b * D + d] = o;
    }
  }

  if (!LAST) {
    __syncthreads();
    const int ii = t >> 2;
    const int q  = t & 3;
    float* ps = s + ((size_t)b * N + ii) * D;
#pragma unroll
    for (int kc = 0; kc < 4; ++kc) {
      const int k0 = kc * 16 + q * 4;
      float4 v;
      v.x = sb[ii][k0 + 0];
      v.y = sb[ii][k0 + 1];
      v.z = sb[ii][k0 + 2];
      v.w = sb[ii][k0 + 3];
      *(float4*)(ps + k0) = v;
    }
  }
}

}  // namespace

extern "C" void kernel_launch(void* const* d_in, const int* in_sizes, int n_in,
                              void* d_out, int out_size, void* d_ws, size_t ws_size,
                              hipStream_t stream)
{
  const float* x  = (const float*)d_in[0];
  const float* ew = (const float*)d_in[1];
  const float* Wm = (const float*)d_in[2];
  const float* bm = (const float*)d_in[3];
  const float* Wu = (const float*)d_in[4];
  const float* bu = (const float*)d_in[5];
  const float* Wo = (const float*)d_in[6];
  const float* bo = (const float*)d_in[7];
  float* out = (float*)d_out;

  float* s   = (float*)d_ws;
  float* agg = s + (size_t)B * N * D;

  const int L = in_sizes[2] / (N * N * E * D);  // = 3

  hipMemsetAsync(agg, 0, (size_t)B * N * D * sizeof(float), stream);

  for (int l = 0; l < L; ++l) {
    const float* sin_p = (l == 0) ? x : s;
    k_msg<<<dim3(N * N, 2), 256, 0, stream>>>(
        sin_p, ew,
        Wm + (size_t)l * N * N * E * D,
        bm + (size_t)l * N * N * D,
        agg);
    if (l < L - 1) {
      k_upd<false><<<B, 256, 0, stream>>>(
          sin_p, s, agg, ew,
          Wu + (size_t)l * 2 * D * D, bu + (size_t)l * D,
          Wo, bo, out);
    } else {
      k_upd<true><<<B, 256, 0, stream>>>(
          sin_p, s, agg, ew,
          Wu + (size_t)l * 2 * D * D, bu + (size_t)l * D,
          Wo, bo, out);
    }
  }
}